// Round 4
// baseline (33.516 us; speedup 1.0000x reference)
//
#include <hip/hip_runtime.h>

// HardUpsampling: seqs [N=16, T=2048, M=256] f32, durations [N, T] i32 in [0,4)
// out = concat( upsampled [N, L, M] f32 , lens [N] (written as f32) )
// L = (out_size - N) / (N*M), known host-side from out_size.
//
// Round 4: back to 2-kernel split (round-2 structure), with:
//  - scatter waves own 8 tokens each: 8 independent row loads in flight
//    (vs 1 in round 2), start offsets from precomputed cum via one 9-lane
//    coalesced read + shfl (NOT the per-wave full-row reduction that sank
//    round 3).
//  - kernel 1 vectorized to int4 (8 loads + 8 stores per lane).
//  - non-temporal loads/stores on the touch-once seqs/out streams.

#define N_ROWS 16
#define T_LEN  2048
#define M_DIM  256
#define M_VEC  (M_DIM / 4)   // 64 float4 per row
#define W_TOK  8             // tokens per wave

typedef float f32x4 __attribute__((ext_vector_type(4)));

// ---------------- Kernel 1: per-row inclusive cumsum + lens ----------------
// grid = N_ROWS blocks, block = 64 (one wave). Lane l owns 32 contiguous
// durations, loaded/stored as int4.
__global__ __launch_bounds__(64) void cumsum_kernel(
    const int* __restrict__ dur, int* __restrict__ cum,
    float* __restrict__ lens_out) {
  const int n = blockIdx.x;
  const int lane = threadIdx.x;            // 0..63
  const int base = n * T_LEN + lane * 32;

  int4 v[8];
#pragma unroll
  for (int j = 0; j < 8; ++j) v[j] = *(const int4*)(dur + base + j * 4);

  int tot = 0;
#pragma unroll
  for (int j = 0; j < 8; ++j) {
    v[j].x = (tot += v[j].x);
    v[j].y = (tot += v[j].y);
    v[j].z = (tot += v[j].z);
    v[j].w = (tot += v[j].w);
  }

  // wave-wide inclusive scan of per-lane totals
  int scan = tot;
#pragma unroll
  for (int d = 1; d < 64; d <<= 1) {
    int t = __shfl_up(scan, d, 64);
    if (lane >= d) scan += t;
  }
  const int excl = scan - tot;

#pragma unroll
  for (int j = 0; j < 8; ++j) {
    int4 o = v[j];
    o.x += excl; o.y += excl; o.z += excl; o.w += excl;
    *(int4*)(cum + base + j * 4) = o;
  }

  if (lane == 63) lens_out[n] = (float)scan;
}

// ---------------- Kernel 2: scatter + pad ----------------
// One wave per 8 consecutive indices [p, p+8). 4 waves / 256-thr block.
//  - token duty (p+k < T): read row once (8 loads in flight), write to
//    output rows [cum[p+k-1], cum[p+k]) — each output row exactly once.
//  - pad duty (len <= p+k < max_len): zero row.
__global__ __launch_bounds__(256) void scatter_kernel(
    const f32x4* __restrict__ seqs4, const int* __restrict__ cum,
    f32x4* __restrict__ out4, int max_len) {
  const int lane = threadIdx.x & 63;
  const int wave = threadIdx.x >> 6;
  const int n = blockIdx.y;
  const int p = (blockIdx.x * 4 + wave) * W_TOK;

  const int* __restrict__ c = cum + n * T_LEN;
  const int len = c[T_LEN - 1];            // wave-uniform broadcast

  // lanes 0..8 read boundaries c[p-1+lane] (clamped); shfl distributes.
  int cb = 0;
  if (lane <= W_TOK) {
    int j = p - 1 + lane;
    if (j < 0) j = 0; else if (j >= T_LEN) j = T_LEN - 1;
    cb = (p - 1 + lane < 0) ? 0 : c[j];
  }

  int st[W_TOK], dk[W_TOK];
#pragma unroll
  for (int k = 0; k < W_TOK; ++k) {
    const int c0 = __shfl(cb, k, 64);      // cum before token p+k
    const int c1 = __shfl(cb, k + 1, 64);  // cum through token p+k
    st[k] = c0;
    dk[k] = (p + k < T_LEN) ? (c1 - c0) : 0;
  }

  const f32x4* __restrict__ srow = seqs4 + (size_t)n * T_LEN * M_VEC + lane;
  f32x4* __restrict__ orow = out4 + (size_t)n * max_len * M_VEC + lane;

  // preload: up to 8 independent non-temporal row loads in flight
  f32x4 v[W_TOK];
#pragma unroll
  for (int k = 0; k < W_TOK; ++k) {
    v[k] = (f32x4)0.f;
    if (dk[k] > 0)
      v[k] = __builtin_nontemporal_load(srow + (size_t)(p + k) * M_VEC);
  }

  // scatter
#pragma unroll
  for (int k = 0; k < W_TOK; ++k) {
    for (int i = st[k]; i < st[k] + dk[k]; ++i)
      __builtin_nontemporal_store(v[k], orow + (size_t)i * M_VEC);
  }

  // padding
  const f32x4 z = (f32x4)0.f;
#pragma unroll
  for (int k = 0; k < W_TOK; ++k) {
    const int i = p + k;
    if (i >= len && i < max_len)
      __builtin_nontemporal_store(z, orow + (size_t)i * M_VEC);
  }
}

extern "C" void kernel_launch(void* const* d_in, const int* in_sizes, int n_in,
                              void* d_out, int out_size, void* d_ws, size_t ws_size,
                              hipStream_t stream) {
  const float* seqs = (const float*)d_in[0];       // [16, 2048, 256] f32
  const int* durations = (const int*)d_in[1];      // [16, 2048] i32
  float* out = (float*)d_out;

  const int N = N_ROWS;
  const int M = M_DIM;
  const int max_len = (out_size - N) / (N * M);    // padded output length L

  int* cum = (int*)d_ws;                           // N*T ints = 128 KiB scratch
  float* lens_out = out + (size_t)N * max_len * M; // lens chunk (as f32 values)

  cumsum_kernel<<<dim3(N), dim3(64), 0, stream>>>(durations, cum, lens_out);

  const int span = (max_len > T_LEN) ? max_len : T_LEN;
  dim3 grid((span + 4 * W_TOK - 1) / (4 * W_TOK), N);
  scatter_kernel<<<grid, dim3(256), 0, stream>>>(
      (const f32x4*)seqs, cum, (f32x4*)out, max_len);
}

// Round 5
// 22.474 us; speedup vs baseline: 1.4913x; 1.4913x over previous
//
#include <hip/hip_runtime.h>

// HardUpsampling: seqs [N=16, T=2048, M=256] f32, durations [N, T] i32 in [0,4)
// out = concat( upsampled [N, L, M] f32 , lens [N] (written as f32) )
//
// Round 5: R2 two-kernel structure, no non-temporal ops (R4's -10us confound).
//  - k1: 256-thread block scan per row (4x wider than R2's 64-thread version).
//  - k2: W_TOK=4 tokens/wave -> 4 independent row loads in flight; since
//    d in [0,3], scatter is 3 predicated stores per token (no runtime loop).

#define N_ROWS 16
#define T_LEN  2048
#define M_DIM  256
#define M_VEC  (M_DIM / 4)   // 64 float4 per row
#define W_TOK  4             // tokens per wave

typedef float f32x4 __attribute__((ext_vector_type(4)));

// ---------------- Kernel 1: per-row inclusive cumsum + lens ----------------
// grid = N_ROWS blocks, block = 256 (4 waves). Thread t owns 8 contiguous
// durations (2x int4); wave scan + LDS cross-wave combine.
__global__ __launch_bounds__(256) void cumsum_kernel(
    const int* __restrict__ dur, int* __restrict__ cum,
    float* __restrict__ lens_out) {
  const int n = blockIdx.x;
  const int tid = threadIdx.x;
  const int lane = tid & 63;
  const int wv = tid >> 6;
  const int base = n * T_LEN + tid * 8;

  int4 a = *(const int4*)(dur + base);
  int4 b = *(const int4*)(dur + base + 4);

  int tot = 0;
  a.x = (tot += a.x); a.y = (tot += a.y); a.z = (tot += a.z); a.w = (tot += a.w);
  b.x = (tot += b.x); b.y = (tot += b.y); b.z = (tot += b.z); b.w = (tot += b.w);

  // wave-wide inclusive scan of per-thread totals
  int scan = tot;
#pragma unroll
  for (int d = 1; d < 64; d <<= 1) {
    int t = __shfl_up(scan, d, 64);
    if (lane >= d) scan += t;
  }

  __shared__ int wtot[4];
  if (lane == 63) wtot[wv] = scan;
  __syncthreads();

  int woff = 0;
#pragma unroll
  for (int w = 0; w < 3; ++w) woff += (w < wv) ? wtot[w] : 0;

  const int excl = woff + scan - tot;      // exclusive prefix for this thread
  a.x += excl; a.y += excl; a.z += excl; a.w += excl;
  b.x += excl; b.y += excl; b.z += excl; b.w += excl;
  *(int4*)(cum + base) = a;
  *(int4*)(cum + base + 4) = b;

  if (tid == 255) lens_out[n] = (float)(woff + scan);
}

// ---------------- Kernel 2: scatter + pad ----------------
// One wave per 4 consecutive indices [p, p+4). 4 waves / 256-thr block.
__global__ __launch_bounds__(256) void scatter_kernel(
    const f32x4* __restrict__ seqs4, const int* __restrict__ cum,
    f32x4* __restrict__ out4, int max_len) {
  const int lane = threadIdx.x & 63;
  const int wave = threadIdx.x >> 6;
  const int n = blockIdx.y;
  const int p = (blockIdx.x * 4 + wave) * W_TOK;

  const int* __restrict__ c = cum + n * T_LEN;
  const int len = c[T_LEN - 1];            // wave-uniform broadcast

  // lanes 0..4 read boundaries c[p-1+lane] (clamped); shfl distributes.
  int cb = 0;
  if (lane <= W_TOK) {
    int j = p - 1 + lane;
    if (j < 0) j = 0; else if (j >= T_LEN) j = T_LEN - 1;
    cb = (p - 1 + lane < 0) ? 0 : c[j];
  }

  int st[W_TOK], dk[W_TOK];
#pragma unroll
  for (int k = 0; k < W_TOK; ++k) {
    const int c0 = __shfl(cb, k, 64);
    const int c1 = __shfl(cb, k + 1, 64);
    st[k] = c0;
    dk[k] = (p + k < T_LEN) ? (c1 - c0) : 0;   // 0..3
  }

  const f32x4* __restrict__ srow = seqs4 + (size_t)n * T_LEN * M_VEC + lane;
  f32x4* __restrict__ orow = out4 + (size_t)n * max_len * M_VEC + lane;

  // preload: up to 4 independent row loads in flight
  f32x4 v[W_TOK];
#pragma unroll
  for (int k = 0; k < W_TOK; ++k) {
    v[k] = (f32x4)0.f;
    if (dk[k] > 0) v[k] = srow[(size_t)(p + k) * M_VEC];
  }

  // scatter: d<=3 -> 3 predicated stores per token, no runtime loop
#pragma unroll
  for (int k = 0; k < W_TOK; ++k) {
    if (dk[k] > 0) orow[(size_t)(st[k] + 0) * M_VEC] = v[k];
    if (dk[k] > 1) orow[(size_t)(st[k] + 1) * M_VEC] = v[k];
    if (dk[k] > 2) orow[(size_t)(st[k] + 2) * M_VEC] = v[k];
  }

  // padding: output rows [len, max_len) in this wave's range
  const f32x4 z = (f32x4)0.f;
#pragma unroll
  for (int k = 0; k < W_TOK; ++k) {
    const int i = p + k;
    if (i >= len && i < max_len) orow[(size_t)i * M_VEC] = z;
  }
}

extern "C" void kernel_launch(void* const* d_in, const int* in_sizes, int n_in,
                              void* d_out, int out_size, void* d_ws, size_t ws_size,
                              hipStream_t stream) {
  const float* seqs = (const float*)d_in[0];       // [16, 2048, 256] f32
  const int* durations = (const int*)d_in[1];      // [16, 2048] i32
  float* out = (float*)d_out;

  const int N = N_ROWS;
  const int M = M_DIM;
  const int max_len = (out_size - N) / (N * M);    // padded output length L

  int* cum = (int*)d_ws;                           // N*T ints = 128 KiB scratch
  float* lens_out = out + (size_t)N * max_len * M; // lens chunk (as f32 values)

  cumsum_kernel<<<dim3(N), dim3(256), 0, stream>>>(durations, cum, lens_out);

  const int span = (max_len > T_LEN) ? max_len : T_LEN;
  dim3 grid((span + 4 * W_TOK - 1) / (4 * W_TOK), N);
  scatter_kernel<<<grid, dim3(256), 0, stream>>>(
      (const f32x4*)seqs, cum, (f32x4*)out, max_len);
}